// Round 8
// baseline (168.968 us; speedup 1.0000x reference)
//
#include <hip/hip_runtime.h>
#include <math.h>

#define BB 4
#define HH 8
#define LL 2048
#define DD 64
#define SK 40            // sample_k == u == 40 for L=2048, FACTOR=5
#define BH (BB*HH)       // 32

__device__ __forceinline__ unsigned ordu(float v) {
    unsigned u = __float_as_uint(v);
    return (u & 0x80000000u) ? ~u : (u | 0x80000000u);
}

// ---------------------------------------------------------------------------
// Stage 1: blocks [0,1024) compute M; blocks [1024,1536) compute V chunk sums.
__global__ __launch_bounds__(256) void stage1_kernel(
        const float* __restrict__ Q, const float* __restrict__ K,
        const float* __restrict__ V, const int* __restrict__ IDX,
        float* __restrict__ M, float* __restrict__ csum) {
    int tid = threadIdx.x;
    if (blockIdx.x < 1024) {
        // ----- compute_M: 4 lanes/query, 16 queries/wave, 64 queries/block,
        // depth-2 software pipeline (2 samples' K rows in flight + idx 4-ahead)
        int x = blockIdx.x;
        int bhLo = x & 7;
        int r = x >> 3;                   // [0,128)
        int bhHi = r & 3;
        int chunk = r >> 2;               // [0,32)
        int bh = bhHi * 8 + bhLo;
        int qbase = chunk * 64;
        int w = tid >> 6, lane = tid & 63;
        int qw = lane >> 2, c = lane & 3;
        int qi = w * 16 + qw;
        int qpos = qbase + qi;

        __shared__ int sidx[64 * SK];     // 10 KB
        for (int i = tid; i < 64 * SK; i += 256) sidx[i] = IDX[(size_t)qbase * SK + i];

        const float4* Q4 = (const float4*)Q;
        const float4* K4 = (const float4*)K;
        float4 qreg[4];
        #pragma unroll
        for (int j = 0; j < 4; ++j)
            qreg[j] = Q4[((size_t)bh * LL + qpos) * 16 + j * 4 + c];
        __syncthreads();

        size_t kb4 = (size_t)bh * LL * 16;
        const int* myidx = sidx + qi * SK;

        int iA = myidx[0], iB = myidx[1];
        float4 A[4], B[4];
        #pragma unroll
        for (int j = 0; j < 4; ++j) {
            A[j] = K4[kb4 + (size_t)iA * 16 + j * 4 + c];
            B[j] = K4[kb4 + (size_t)iB * 16 + j * 4 + c];
        }
        int iC = myidx[2], iD = myidx[3];

        float mx = -INFINITY, sm = 0.f;
        for (int s = 0; s < SK; s += 2) {
            float4 Cr[4], Dr[4];
            if (s + 2 < SK) {
                #pragma unroll
                for (int j = 0; j < 4; ++j) {
                    Cr[j] = K4[kb4 + (size_t)iC * 16 + j * 4 + c];
                    Dr[j] = K4[kb4 + (size_t)iD * 16 + j * 4 + c];
                }
                // next-next sample indices; s even & SK even => s+5 <= SK-1
                if (s + 4 < SK) { iC = myidx[s + 4]; iD = myidx[s + 5]; }
            }
            float p0 = 0.f, p1 = 0.f;
            #pragma unroll
            for (int j = 0; j < 4; ++j) {
                p0 += A[j].x * qreg[j].x + A[j].y * qreg[j].y + A[j].z * qreg[j].z + A[j].w * qreg[j].w;
                p1 += B[j].x * qreg[j].x + B[j].y * qreg[j].y + B[j].z * qreg[j].z + B[j].w * qreg[j].w;
            }
            p0 += __shfl_xor(p0, 1, 64);
            p0 += __shfl_xor(p0, 2, 64);
            p1 += __shfl_xor(p1, 1, 64);
            p1 += __shfl_xor(p1, 2, 64);
            mx = fmaxf(mx, fmaxf(p0, p1));
            sm += p0 + p1;
            #pragma unroll
            for (int j = 0; j < 4; ++j) { A[j] = Cr[j]; B[j] = Dr[j]; }
        }
        if (c == 0) M[(size_t)bh * LL + qpos] = mx - sm * (1.0f / (float)LL);
    } else {
        // ----- vsum: per-(bh,chunk-of-128) column sums of V
        int x = blockIdx.x - 1024;        // [0,512)
        int bhLo = x & 7, r = x >> 3;
        int bhHi = r & 3, c = r >> 2;     // c in [0,16)
        int bh = bhHi * 8 + bhLo;
        int d = tid & 63, sg = tid >> 6;
        size_t base = (size_t)bh * LL * DD;
        int row0 = c * 128 + sg * 32;
        float s = 0.f;
        for (int j = 0; j < 32; ++j) s += V[base + (size_t)(row0 + j) * DD + d];
        __shared__ float part[4][DD];
        part[sg][d] = s;
        __syncthreads();
        if (sg == 0)
            csum[((size_t)bh * 16 + c) * DD + d] = part[0][d] + part[1][d] + part[2][d] + part[3][d];
    }
}

// ---------------------------------------------------------------------------
// Stage 2: blocks [0,512) cumsum V -> out; blocks [512,544) radix top-40 of M,
// emitted DESCENDING by qpos (longest-first for stage-3 scheduling).
__global__ __launch_bounds__(256) void stage2_kernel(
        const float* __restrict__ V, const float* __restrict__ csum,
        const float* __restrict__ M, float* __restrict__ out,
        int* __restrict__ topk) {
    int tid = threadIdx.x;
    if (blockIdx.x < 512) {
        // ----- cumsum
        int x = blockIdx.x;
        int bhLo = x & 7, r = x >> 3;
        int bhHi = r & 3, c = r >> 2;
        int bh = bhHi * 8 + bhLo;
        int d = tid & 63, sg = tid >> 6;
        size_t base = (size_t)bh * LL * DD;
        int row0 = c * 128 + sg * 32;
        float v[32];
        #pragma unroll
        for (int j = 0; j < 32; ++j) v[j] = V[base + (size_t)(row0 + j) * DD + d];
        float s = 0.f;
        #pragma unroll
        for (int j = 0; j < 32; ++j) s += v[j];
        __shared__ float part[4][DD];
        part[sg][d] = s;
        __syncthreads();
        float pre = 0.f;
        for (int cc = 0; cc < c; ++cc) pre += csum[((size_t)bh * 16 + cc) * DD + d];
        for (int ss = 0; ss < sg; ++ss) pre += part[ss][d];
        float acc = pre;
        #pragma unroll
        for (int j = 0; j < 32; ++j) {
            acc += v[j];
            out[base + (size_t)(row0 + j) * DD + d] = acc;
        }
    } else {
        // ----- radix top-40 (8 bits/pass, 4 passes); then sort desc by index.
        int bh = blockIdx.x - 512;
        __shared__ unsigned hist[256];
        __shared__ unsigned bc_prefix, bc_need;
        __shared__ unsigned cnt_gt, cnt_eq;
        __shared__ int eqlist[128];
        __shared__ int sel[SK];

        unsigned v[8];
        #pragma unroll
        for (int j = 0; j < 8; ++j)
            v[j] = ordu(M[(size_t)bh * LL + tid + j * 256]);

        unsigned prefix = 0, need = SK;
        #pragma unroll
        for (int pass = 0; pass < 4; ++pass) {
            const int s = 24 - 8 * pass;
            const unsigned maskHigh = (pass == 0) ? 0u : (0xFFFFFFFFu << (s + 8));
            hist[tid] = 0;
            __syncthreads();
            #pragma unroll
            for (int j = 0; j < 8; ++j)
                if (((v[j] ^ prefix) & maskHigh) == 0)
                    atomicAdd(&hist[(v[j] >> s) & 0xFF], 1u);
            __syncthreads();
            unsigned above = 0;
            for (int b = tid + 1; b < 256; ++b) above += hist[b];
            if (above < need && above + hist[tid] >= need) {
                bc_prefix = prefix | ((unsigned)tid << s);
                bc_need = need - above;
            }
            __syncthreads();
            prefix = bc_prefix;
            need = bc_need;
            __syncthreads();
        }
        unsigned T = prefix;
        if (tid == 0) { cnt_gt = 0; cnt_eq = 0; }
        __syncthreads();
        #pragma unroll
        for (int j = 0; j < 8; ++j) {
            int idx = tid + j * 256;
            if (v[j] > T) { unsigned p = atomicAdd(&cnt_gt, 1u); sel[p] = idx; }
            else if (v[j] == T) { unsigned p = atomicAdd(&cnt_eq, 1u); if (p < 128) eqlist[p] = idx; }
        }
        __syncthreads();
        if (tid == 0) {
            int ne = (int)min(cnt_eq, 128u);
            unsigned base = cnt_gt;       // == SK - need
            for (unsigned r2 = 0; r2 < need; ++r2) {
                int bj = 0, bv = 0x7FFFFFFF;
                for (int j = 0; j < ne; ++j)
                    if (eqlist[j] < bv) { bv = eqlist[j]; bj = j; }
                sel[base + r2] = bv;
                eqlist[bj] = 0x7FFFFFFF;
            }
        }
        __syncthreads();
        // rank-sort descending by qpos (indices distinct): longest rows first
        if (tid < SK) {
            int mine = sel[tid];
            int rank = 0;
            #pragma unroll
            for (int j = 0; j < SK; ++j) rank += (sel[j] > mine);
            topk[bh * SK + rank] = mine;
        }
    }
}

// ---------------------------------------------------------------------------
// Stage 3: one block per (bh,u): full causal softmax attention over keys
// [0..qpos]. Block map: bh = x&31 (XCD spread), u = x>>5 (longest-first).
// Score rounds and PV loop software-prefetched.
__global__ __launch_bounds__(256) void attn_kernel(
        const float* __restrict__ Q, const float* __restrict__ K,
        const float* __restrict__ V, const int* __restrict__ topk,
        float* __restrict__ out) {
    int x = blockIdx.x;               // 1280
    int bh = x & 31;
    int u = x >> 5;
    int tid = threadIdx.x;

    int qpos = topk[bh * SK + u];
    int nk = qpos + 1;

    const float4* Q4 = (const float4*)Q;
    const float4* K4 = (const float4*)K;
    const float4* V4 = (const float4*)V;

    int w = tid >> 6, lane = tid & 63;
    int kw = lane >> 2, c = lane & 3;
    float4 qreg[4];
    #pragma unroll
    for (int j = 0; j < 4; ++j)
        qreg[j] = Q4[((size_t)bh * LL + qpos) * 16 + j * 4 + c];

    __shared__ float sc[LL];          // 8 KB
    __shared__ float red[4], red2[4];
    __shared__ float opart[16][16][4];

    // score phase: 4 lanes/key, 64 keys/block-round, prefetch next round
    size_t kb4 = (size_t)bh * LL * 16;
    int rounds = (nk + 63) >> 6;
    int key0 = w * 16 + kw;
    float4 A[4];
    if (key0 < nk) {
        #pragma unroll
        for (int j = 0; j < 4; ++j) A[j] = K4[kb4 + (size_t)key0 * 16 + j * 4 + c];
    }
    for (int rr = 0; rr < rounds; ++rr) {
        int key = rr * 64 + key0;
        int keyn = key + 64;
        float4 B[4];
        if (rr + 1 < rounds && keyn < nk) {
            #pragma unroll
            for (int j = 0; j < 4; ++j) B[j] = K4[kb4 + (size_t)keyn * 16 + j * 4 + c];
        }
        if (key < nk) {
            float p = 0.f;
            #pragma unroll
            for (int j = 0; j < 4; ++j)
                p += A[j].x * qreg[j].x + A[j].y * qreg[j].y + A[j].z * qreg[j].z + A[j].w * qreg[j].w;
            p += __shfl_xor(p, 1, 64);
            p += __shfl_xor(p, 2, 64);
            if (c == 0) sc[key] = p * 0.125f;   // 1/sqrt(64)
        }
        #pragma unroll
        for (int j = 0; j < 4; ++j) A[j] = B[j];
    }
    __syncthreads();

    // block max over sc[0..nk)
    float m = -INFINITY;
    for (int j = tid; j < nk; j += 256) m = fmaxf(m, sc[j]);
    #pragma unroll
    for (int off = 32; off > 0; off >>= 1) m = fmaxf(m, __shfl_xor(m, off, 64));
    if (lane == 0) red[w] = m;
    __syncthreads();
    m = fmaxf(fmaxf(red[0], red[1]), fmaxf(red[2], red[3]));

    // exp + block sum
    float ls = 0.f;
    for (int j = tid; j < nk; j += 256) {
        float e = expf(sc[j] - m);
        sc[j] = e;
        ls += e;
    }
    #pragma unroll
    for (int off = 32; off > 0; off >>= 1) ls += __shfl_xor(ls, off, 64);
    if (lane == 0) red2[w] = ls;
    __syncthreads();
    float linv = 1.0f / (red2[0] + red2[1] + red2[2] + red2[3]);

    // weighted V: 16 k-groups x 16 float4 columns, depth-2 prefetch
    int col4 = tid & 15, kg = tid >> 4;
    float ax = 0.f, ay = 0.f, az = 0.f, aw = 0.f;
    size_t vb4 = (size_t)bh * LL * 16;
    float4 Va = make_float4(0.f, 0.f, 0.f, 0.f);
    float4 Vb = make_float4(0.f, 0.f, 0.f, 0.f);
    if (kg < nk)      Va = V4[vb4 + (size_t)kg * 16 + col4];
    if (kg + 16 < nk) Vb = V4[vb4 + (size_t)(kg + 16) * 16 + col4];
    for (int j = kg; j < nk; j += 16) {
        float4 Vc = make_float4(0.f, 0.f, 0.f, 0.f);
        if (j + 32 < nk) Vc = V4[vb4 + (size_t)(j + 32) * 16 + col4];
        float sj = sc[j];
        ax += sj * Va.x; ay += sj * Va.y; az += sj * Va.z; aw += sj * Va.w;
        Va = Vb; Vb = Vc;
    }
    opart[kg][col4][0] = ax;
    opart[kg][col4][1] = ay;
    opart[kg][col4][2] = az;
    opart[kg][col4][3] = aw;
    __syncthreads();
    if (tid < DD) {
        int c4 = tid >> 2, cp = tid & 3;
        float s = 0.f;
        #pragma unroll
        for (int kg2 = 0; kg2 < 16; ++kg2) s += opart[kg2][c4][cp];
        out[((size_t)bh * LL + qpos) * DD + tid] = s * linv;
    }
}

// ---------------------------------------------------------------------------
extern "C" void kernel_launch(void* const* d_in, const int* in_sizes, int n_in,
                              void* d_out, int out_size, void* d_ws, size_t ws_size,
                              hipStream_t stream) {
    const float* Q   = (const float*)d_in[0];
    const float* K   = (const float*)d_in[1];
    const float* V   = (const float*)d_in[2];
    const int*   IDX = (const int*)d_in[3];
    float* out = (float*)d_out;

    char* ws = (char*)d_ws;
    float* M    = (float*)ws;  ws += (size_t)BH * LL * sizeof(float);                 // 256 KB
    int*   topk = (int*)ws;    ws += ((size_t)BH * SK * sizeof(int) + 255) & ~255ull;
    float* csum = (float*)ws;  // BH*16*DD floats = 128 KB

    stage1_kernel<<<1536, 256, 0, stream>>>(Q, K, V, IDX, M, csum);
    stage2_kernel<<<544, 256, 0, stream>>>(V, csum, M, out, topk);
    attn_kernel<<<BH * SK, 256, 0, stream>>>(Q, K, V, topk, out);
}